// Round 2
// baseline (1560.044 us; speedup 1.0000x reference)
//
#include <hip/hip_runtime.h>
#include <hip/hip_bf16.h>

typedef __hip_bfloat16 bf16;
typedef float f32x4 __attribute__((ext_vector_type(4)));
typedef short bf16x8 __attribute__((ext_vector_type(8)));  // 8 bf16 in 4 VGPRs
typedef short bf16x4 __attribute__((ext_vector_type(4)));  // 4 bf16 in 2 VGPRs

#define D_MODEL 4096
#define N_HEADS 32
#define N_KV 8
#define HEAD_DIM 128
#define SEQ 2048
#define BATCH 2
#define NTOK (BATCH * SEQ)  // 4096

static __device__ __forceinline__ float b2f(bf16 v) { return __bfloat162float(v); }
static __device__ __forceinline__ bf16 f2b(float v) { return __float2bfloat16(v); }
static __device__ __forceinline__ short f2bs(float v) {
  union { bf16 b; short s; } u; u.b = f2b(v); return u.s;
}

// async global->LDS, 16B per lane; lds dest must be wave-uniform base (+ lane*16B implicit)
static __device__ __forceinline__ void async_ld16(const bf16* g, bf16* l) {
  __builtin_amdgcn_global_load_lds(
      (const __attribute__((address_space(1))) void*)g,
      (__attribute__((address_space(3))) void*)l, 16, 0, 0);
}

// ---------------------------------------------------------------- cast x -> bf16
__global__ __launch_bounds__(256) void cast_f32_to_bf16(const float* __restrict__ in,
                                                        bf16* __restrict__ out, int n4) {
  int i = blockIdx.x * 256 + threadIdx.x;
  if (i >= n4) return;
  float4 v = ((const float4*)in)[i];
  union { ushort4 u; bf16 b[4]; } o;
  o.b[0] = f2b(v.x); o.b[1] = f2b(v.y); o.b[2] = f2b(v.z); o.b[3] = f2b(v.w);
  ((ushort4*)out)[i] = o.u;
}

// ------------------------------------------- transpose+cast: in[R][C] f32 -> out[C][R] bf16
__global__ __launch_bounds__(256) void transpose_cast(const float* __restrict__ in,
                                                      bf16* __restrict__ out, int R, int C) {
  __shared__ bf16 tile[64][65];
  const int c0 = blockIdx.x * 64;
  const int r0 = blockIdx.y * 64;
  const int t = threadIdx.x;
  const int tc = t & 63, tr = t >> 6;  // 4 rows per pass
  for (int i = 0; i < 16; i++) {
    int r = tr + i * 4;
    tile[tc][r] = f2b(in[(size_t)(r0 + r) * C + c0 + tc]);
  }
  __syncthreads();
  for (int i = 0; i < 16; i++) {
    int r = tr + i * 4;  // row of out tile (= col of in)
    out[(size_t)(c0 + r) * R + r0 + tc] = tile[r][tc];
  }
}

// ------------------------------------------- bf16 transpose (per batch): out[b][c][s] = in[b][s][c]
// in: [B*2048][1024], out: [B*1024][2048]
__global__ __launch_bounds__(256) void transpose_v(const bf16* __restrict__ in,
                                                   bf16* __restrict__ out) {
  __shared__ __align__(16) bf16 tile[64][72];
  const int b = blockIdx.z;
  const int s0 = blockIdx.y * 64, c0 = blockIdx.x * 64;
  const int t = threadIdx.x;
  const int rr = t >> 3, g8 = (t & 7) * 8;
#pragma unroll
  for (int i = 0; i < 2; i++) {
    int s = rr + i * 32;
    *(int4*)&tile[s][g8] = *(const int4*)&in[((size_t)(b * 2048 + s0 + s)) * 1024 + c0 + g8];
  }
  __syncthreads();
#pragma unroll
  for (int i = 0; i < 2; i++) {
    int c = rr + i * 32;
    bf16 tmp[8];
#pragma unroll
    for (int j = 0; j < 8; j++) tmp[j] = tile[g8 + j][c];
    *(int4*)&out[((size_t)(b * 1024 + c0 + c)) * 2048 + s0 + g8] = *(int4*)tmp;
  }
}

// ---------------------------------------------------------------- GEMM  C = A * Bt^T
static __device__ __forceinline__ void store_out(float* p, float v) { *p = v; }
static __device__ __forceinline__ void store_out(bf16* p, float v) { *p = f2b(v); }

template <typename OutT>
__global__ __launch_bounds__(256) void gemm_bt(const bf16* __restrict__ A,
                                               const bf16* __restrict__ Bt,
                                               OutT* __restrict__ C,
                                               int M, int N, int K) {
  __shared__ __align__(16) bf16 As[128][32];  // unpadded: required by global_load_lds
  __shared__ __align__(16) bf16 Bs[128][32];
  const int t = threadIdx.x;
  const int m0 = blockIdx.y * 128;
  const int n0 = blockIdx.x * 128;
  const int lane = t & 63, wave = t >> 6;
  const int wm = (wave >> 1) * 64, wn = (wave & 1) * 64;
  const int lr = lane & 15, quad = lane >> 4;

  const int srow = wave * 16 + (lane >> 2);
  const int skg = (lane & 3) << 3;
  const bf16* Ap0 = A + (size_t)(m0 + srow) * K + skg;
  const bf16* Ap1 = A + (size_t)(m0 + 64 + srow) * K + skg;
  const bf16* Bp0 = Bt + (size_t)(n0 + srow) * K + skg;
  const bf16* Bp1 = Bt + (size_t)(n0 + 64 + srow) * K + skg;
  bf16* lA0 = &As[wave * 16][0];
  bf16* lA1 = &As[64 + wave * 16][0];
  bf16* lB0 = &Bs[wave * 16][0];
  bf16* lB1 = &Bs[64 + wave * 16][0];

  f32x4 acc[4][4] = {};

  for (int k0 = 0; k0 < K; k0 += 32) {
    async_ld16(Ap0 + k0, lA0);
    async_ld16(Ap1 + k0, lA1);
    async_ld16(Bp0 + k0, lB0);
    async_ld16(Bp1 + k0, lB1);
    __syncthreads();
    bf16x8 a[4], b[4];
#pragma unroll
    for (int i = 0; i < 4; i++) a[i] = *(const bf16x8*)&As[wm + i * 16 + lr][quad * 8];
#pragma unroll
    for (int j = 0; j < 4; j++) b[j] = *(const bf16x8*)&Bs[wn + j * 16 + lr][quad * 8];
#pragma unroll
    for (int i = 0; i < 4; i++)
#pragma unroll
      for (int j = 0; j < 4; j++)
        acc[i][j] = __builtin_amdgcn_mfma_f32_16x16x32_bf16(a[i], b[j], acc[i][j], 0, 0, 0);
    __syncthreads();
  }
#pragma unroll
  for (int i = 0; i < 4; i++) {
    int row = m0 + wm + i * 16 + quad * 4;
#pragma unroll
    for (int j = 0; j < 4; j++) {
      int col = n0 + wn + j * 16 + lr;
#pragma unroll
      for (int r = 0; r < 4; r++)
        store_out(&C[(size_t)(row + r) * N + col], acc[i][j][r]);
    }
  }
}

// ---------------------------------------------------------------- RoPE (in-place) + scale
__global__ __launch_bounds__(256) void rope_kernel(bf16* __restrict__ X, int lh, float scale) {
  int idx = blockIdx.x * 256 + threadIdx.x;
  int d = idx & 63;
  int rest = idx >> 6;
  int h = rest & ((1 << lh) - 1);
  int tok = rest >> lh;
  float ang = (float)(tok & (SEQ - 1)) * exp2f((float)d * -0.2076205059304602f);  // log2(1e4)/64
  float sn, cs;
  sincosf(ang, &sn, &cs);
  bf16* p = X + (((size_t)tok << lh) + h) * HEAD_DIM + d;
  float x0 = b2f(p[0]), x1 = b2f(p[64]);
  p[0]  = f2b((x0 * cs - x1 * sn) * scale);
  p[64] = f2b((x1 * cs + x0 * sn) * scale);
}

// ---------------------------------------------------------------- flash attention (causal, GQA)
// S^T/O^T formulation, QBLK=256 (16 waves x 16 q rows), KVBLK=64.
// Per staged 32KB tile, 16 waves consume it -> staging/barrier cost per unit
// compute is half of the QBLK=128 version, and 2 blocks/CU = 32 waves/CU (100%
// nominal occupancy). Grid = 512 blocks = exactly the resident capacity (one
// dispatch round, no tail round). Defer-max (T13, THR=8 in log2 domain) skips
// the o_acc rescale on no-growth tiles; setprio(1) wraps both MFMA clusters (T5).
static __device__ __forceinline__ void stage_kv(const bf16* kbase, const bf16* vtbase,
                                                bf16* ksb, bf16* vtb,
                                                int jt, int w) {
  const int lane = threadIdx.x & 63;
  // K tile: 64 rows x 256B = 1024 granules of 16B. LDS(r,g) <- global(r, g^(r&7))
  {
    int G = w * 64 + lane;
    int r = G >> 4;
    int gs = (G & 15) ^ (r & 7);
    async_ld16(kbase + (size_t)(jt * 64 + r) * 1024 + gs * 8, ksb + w * 64 * 8);
  }
  // V^T tile: 128 rows x 128B = 1024 granules. LDS(d,g) <- global(d, g^(d&7))
  {
    int G = w * 64 + lane;
    int d = G >> 3;
    int gs = (G & 7) ^ (d & 7);
    async_ld16(vtbase + (size_t)d * 2048 + jt * 64 + gs * 8, vtb + w * 64 * 8);
  }
}

__global__ __launch_bounds__(1024, 8) void flash_attn(const bf16* __restrict__ Q,
                                                      const bf16* __restrict__ K,
                                                      const bf16* __restrict__ VT,
                                                      bf16* __restrict__ O) {
  __shared__ __align__(16) bf16 Ks[2][64][128];   // 2 x 16 KB
  __shared__ __align__(16) bf16 Vt[2][128][64];   // 2 x 16 KB

  const int qb = (int)gridDim.x - 1 - (int)blockIdx.x;
  const int h = blockIdx.y, b = blockIdx.z;
  const int kvh = h >> 2;  // GROUP = 4
  const int t = threadIdx.x, lane = t & 63, w = t >> 6;  // w in 0..15
  const int lr = lane & 15, quad = lane >> 4;

  const bf16* kbase = K + ((size_t)(b * SEQ) * N_KV + kvh) * HEAD_DIM;
  const bf16* vtbase = VT + (size_t)(b * 1024 + kvh * 128) * 2048;

  // per-lane swizzled LDS read offsets (elements). r&7 == lr&7 for all rows read.
  int koff[4], voff[4];
#pragma unroll
  for (int ks = 0; ks < 4; ks++) koff[ks] = (((ks << 2) + quad) ^ (lr & 7)) << 3;
#pragma unroll
  for (int j = 0; j < 4; j++)
    voff[j] = (((((j << 1) + (quad >> 1)) ^ (lr & 7)) << 3) + ((quad & 1) << 2));

  // this lane's q token (each lane owns exactly one q row of the wave's 16)
  const int sqg = qb * 256 + w * 16;           // wave's lowest q row (global)
  const int tok = b * SEQ + sqg + lr;

  // Q fragments straight from global (post-RoPE): B-frag n=lr, k = ks*32+quad*8+j
  bf16x8 qf[4];
  {
    const bf16* qrow = Q + (size_t)tok * D_MODEL + h * HEAD_DIM + quad * 8;
#pragma unroll
    for (int ks = 0; ks < 4; ks++) qf[ks] = *(const bf16x8*)(qrow + ks * 32);
  }

  f32x4 o_acc[8] = {};          // O^T: d = n*16 + quad*4 + r, q = lr
  float m_i = -1e30f, l_i = 0.f;

  const int nt = 4 * qb + 4;    // kv tiles covering rows [0, qb*256+256)
  bf16* ksc = &Ks[0][0][0]; bf16* vtc = &Vt[0][0][0];
  bf16* ksn = &Ks[1][0][0]; bf16* vtn = &Vt[1][0][0];

  stage_kv(kbase, vtbase, ksc, vtc, 0, w);
  __syncthreads();  // implicit vmcnt(0) before barrier completes the DMA

  for (int jt = 0; jt < nt; jt++) {
    // issue next tile's DMA first: latency hides under this tile's compute
    if (jt + 1 < nt) stage_kv(kbase, vtbase, ksn, vtn, jt + 1, w);

    // waves whose 16 q rows are entirely above this kv tile skip compute
    // (wave-uniform: only possible on the final tiles)
    if (jt * 64 <= sqg + 15) {
      // S^T = K * Q^T : 4 sk-tiles of 16; C-layout: sk = j*16+quad*4+r, q = lr
      f32x4 s_acc[4] = {};
      __builtin_amdgcn_s_setprio(1);
#pragma unroll
      for (int j = 0; j < 4; j++) {
        const bf16* krow = ksc + (j * 16 + lr) * 128;
#pragma unroll
        for (int ks = 0; ks < 4; ks++) {
          bf16x8 kf = *(const bf16x8*)(krow + koff[ks]);
          s_acc[j] = __builtin_amdgcn_mfma_f32_16x16x32_bf16(kf, qf[ks], s_acc[j], 0, 0, 0);
        }
      }
      __builtin_amdgcn_s_setprio(0);

      // causal mask (only tiles reaching the wave's diagonal)
      if ((jt + 1) * 64 > sqg) {
        int sq = sqg + lr;
        int k0 = jt * 64;
#pragma unroll
        for (int j = 0; j < 4; j++)
#pragma unroll
          for (int r = 0; r < 4; r++)
            if (k0 + j * 16 + quad * 4 + r > sq) s_acc[j][r] = -1e30f;
      }

      // online softmax in exp2 domain — per-lane scalars (lane owns q row lr)
      float mx = -1e30f;
#pragma unroll
      for (int j = 0; j < 4; j++)
#pragma unroll
        for (int r = 0; r < 4; r++) mx = fmaxf(mx, s_acc[j][r]);
      mx = fmaxf(mx, __shfl_xor(mx, 16));
      mx = fmaxf(mx, __shfl_xor(mx, 32));

      // defer-max (T13): skip rescale unless the tile max outgrows m_i by >8
      // (P values then bounded by 2^8; f32 accumulation has ample headroom)
      if (!__all(mx <= m_i + 8.f)) {
        float mnew = fmaxf(m_i, mx);
        float alpha = exp2f(m_i - mnew);
        m_i = mnew;
        l_i *= alpha;
#pragma unroll
        for (int n = 0; n < 8; n++)
#pragma unroll
          for (int r = 0; r < 4; r++) o_acc[n][r] *= alpha;
      }

      float p[4][4];
      float sum = 0.f;
#pragma unroll
      for (int j = 0; j < 4; j++)
#pragma unroll
        for (int r = 0; r < 4; r++) {
          p[j][r] = exp2f(s_acc[j][r] - m_i);
          sum += p[j][r];
        }
      sum += __shfl_xor(sum, 16);
      sum += __shfl_xor(sum, 32);
      l_i += sum;

      // pack P into 16x16x16 B-fragments (k = quad*4 + r) — in registers, no LDS
      bf16x4 pf[4];
#pragma unroll
      for (int j = 0; j < 4; j++) {
        pf[j][0] = f2bs(p[j][0]); pf[j][1] = f2bs(p[j][1]);
        pf[j][2] = f2bs(p[j][2]); pf[j][3] = f2bs(p[j][3]);
      }

      // O^T += V^T * P^T  (K=16 per mfma, 4 sk-chunks x 8 d-tiles)
      __builtin_amdgcn_s_setprio(1);
#pragma unroll
      for (int j = 0; j < 4; j++)
#pragma unroll
        for (int n = 0; n < 8; n++) {
          bf16x4 vf = *(const bf16x4*)(vtc + (n * 16 + lr) * 64 + voff[j]);
          o_acc[n] = __builtin_amdgcn_mfma_f32_16x16x16bf16_1k(vf, pf[j], o_acc[n], 0, 0, 0);
        }
      __builtin_amdgcn_s_setprio(0);
    }

    __syncthreads();  // readers done with cur + this wave's DMA into next drained
    bf16* tp;
    tp = ksc; ksc = ksn; ksn = tp;
    tp = vtc; vtc = vtn; vtn = tp;
  }

  // epilogue: O[tok][h*128 + d] = o_acc / l ; d = n*16 + quad*4 + r (4 consecutive)
  {
    float inv_l = 1.f / l_i;
    bf16* obase = O + (size_t)tok * D_MODEL + h * HEAD_DIM + quad * 4;
#pragma unroll
    for (int n = 0; n < 8; n++) {
      bf16x4 ov;
      ov[0] = f2bs(o_acc[n][0] * inv_l); ov[1] = f2bs(o_acc[n][1] * inv_l);
      ov[2] = f2bs(o_acc[n][2] * inv_l); ov[3] = f2bs(o_acc[n][3] * inv_l);
      *(bf16x4*)(obase + n * 16) = ov;
    }
  }
}

// ---------------------------------------------------------------- launcher
extern "C" void kernel_launch(void* const* d_in, const int* in_sizes, int n_in,
                              void* d_out, int out_size, void* d_ws, size_t ws_size,
                              hipStream_t stream) {
  const float* x  = (const float*)d_in[0];
  // d_in[1] = mask: exactly causal (triu k=1) -> hard-coded in flash kernel
  const float* Wq = (const float*)d_in[2];
  const float* Wk = (const float*)d_in[3];
  const float* Wv = (const float*)d_in[4];
  const float* Wo = (const float*)d_in[5];
  float* out = (float*)d_out;

  char* ws = (char*)d_ws;
  const size_t MB = 1024 * 1024;
  bf16* xb  = (bf16*)(ws + 0);         // 32 MB  [4096][4096]
  bf16* WqT = (bf16*)(ws + 32 * MB);   // 32 MB  (dead after Q gemm; reused as Ob)
  bf16* WkT = (bf16*)(ws + 64 * MB);   // 8 MB   [1024][4096]
  bf16* WvT = (bf16*)(ws + 72 * MB);   // 8 MB
  bf16* WoT = (bf16*)(ws + 80 * MB);   // 32 MB
  bf16* Qb  = (bf16*)(ws + 112 * MB);  // 32 MB  [4096][4096]
  bf16* Kb  = (bf16*)(ws + 144 * MB);  // 8 MB   [4096][1024]
  bf16* Vb  = (bf16*)(ws + 152 * MB);  // 8 MB
  bf16* VTb = (bf16*)(ws + 160 * MB);  // 8 MB   [B*1024][2048]
  bf16* Ob  = WqT;                     // alias: WqT unused after Q projection

  // 1. cast activations
  cast_f32_to_bf16<<<dim3(NTOK * D_MODEL / 4 / 256), 256, 0, stream>>>(x, xb, NTOK * D_MODEL / 4);
  // 2. transpose-cast weights to [N][K] bf16
  transpose_cast<<<dim3(D_MODEL / 64, D_MODEL / 64), 256, 0, stream>>>(Wq, WqT, D_MODEL, D_MODEL);
  transpose_cast<<<dim3(1024 / 64, D_MODEL / 64), 256, 0, stream>>>(Wk, WkT, D_MODEL, 1024);
  transpose_cast<<<dim3(1024 / 64, D_MODEL / 64), 256, 0, stream>>>(Wv, WvT, D_MODEL, 1024);
  transpose_cast<<<dim3(D_MODEL / 64, D_MODEL / 64), 256, 0, stream>>>(Wo, WoT, D_MODEL, D_MODEL);
  // 3. projections (bf16 out)
  gemm_bt<bf16><<<dim3(D_MODEL / 128, NTOK / 128), 256, 0, stream>>>(xb, WqT, Qb, NTOK, D_MODEL, D_MODEL);
  gemm_bt<bf16><<<dim3(1024 / 128, NTOK / 128), 256, 0, stream>>>(xb, WkT, Kb, NTOK, 1024, D_MODEL);
  gemm_bt<bf16><<<dim3(1024 / 128, NTOK / 128), 256, 0, stream>>>(xb, WvT, Vb, NTOK, 1024, D_MODEL);
  // 4. RoPE; Q scale = head_dim^-0.5 * log2(e)  (softmax runs in exp2 domain)
  rope_kernel<<<dim3(NTOK * N_HEADS * 64 / 256), 256, 0, stream>>>(Qb, 5, 0.12751741737890f);
  rope_kernel<<<dim3(NTOK * N_KV * 64 / 256), 256, 0, stream>>>(Kb, 3, 1.0f);
  // 5. pre-transpose V per batch: VT[b][c][s]
  transpose_v<<<dim3(1024 / 64, SEQ / 64, BATCH), 256, 0, stream>>>(Vb, VTb);
  // 6. attention (QBLK=256, 16 waves, double-buffered async staging)
  flash_attn<<<dim3(SEQ / 256, N_HEADS, BATCH), 1024, 0, stream>>>(Qb, Kb, VTb, Ob);
  // 7. output projection (fp32 out)
  gemm_bt<float><<<dim3(D_MODEL / 128, NTOK / 128), 256, 0, stream>>>(Ob, WoT, out, NTOK, D_MODEL, D_MODEL);
}

// Round 3
// 914.563 us; speedup vs baseline: 1.7058x; 1.7058x over previous
//
#include <hip/hip_runtime.h>
#include <hip/hip_bf16.h>

typedef __hip_bfloat16 bf16;
typedef float f32x4 __attribute__((ext_vector_type(4)));
typedef short bf16x8 __attribute__((ext_vector_type(8)));  // 8 bf16 in 4 VGPRs
typedef short bf16x4 __attribute__((ext_vector_type(4)));  // 4 bf16 in 2 VGPRs

#define D_MODEL 4096
#define N_HEADS 32
#define N_KV 8
#define HEAD_DIM 128
#define SEQ 2048
#define BATCH 2
#define NTOK (BATCH * SEQ)  // 4096

static __device__ __forceinline__ float b2f(bf16 v) { return __bfloat162float(v); }
static __device__ __forceinline__ bf16 f2b(float v) { return __float2bfloat16(v); }
static __device__ __forceinline__ short f2bs(float v) {
  union { bf16 b; short s; } u; u.b = f2b(v); return u.s;
}

// async global->LDS, 16B per lane; lds dest must be wave-uniform base (+ lane*16B implicit)
static __device__ __forceinline__ void async_ld16(const bf16* g, bf16* l) {
  __builtin_amdgcn_global_load_lds(
      (const __attribute__((address_space(1))) void*)g,
      (__attribute__((address_space(3))) void*)l, 16, 0, 0);
}

// ---------------------------------------------------------------- cast x -> bf16
__global__ __launch_bounds__(256) void cast_f32_to_bf16(const float* __restrict__ in,
                                                        bf16* __restrict__ out, int n4) {
  int i = blockIdx.x * 256 + threadIdx.x;
  if (i >= n4) return;
  float4 v = ((const float4*)in)[i];
  union { ushort4 u; bf16 b[4]; } o;
  o.b[0] = f2b(v.x); o.b[1] = f2b(v.y); o.b[2] = f2b(v.z); o.b[3] = f2b(v.w);
  ((ushort4*)out)[i] = o.u;
}

// ------------------------------------------- transpose+cast: in[R][C] f32 -> out[C][R] bf16
__global__ __launch_bounds__(256) void transpose_cast(const float* __restrict__ in,
                                                      bf16* __restrict__ out, int R, int C) {
  __shared__ bf16 tile[64][65];
  const int c0 = blockIdx.x * 64;
  const int r0 = blockIdx.y * 64;
  const int t = threadIdx.x;
  const int tc = t & 63, tr = t >> 6;  // 4 rows per pass
  for (int i = 0; i < 16; i++) {
    int r = tr + i * 4;
    tile[tc][r] = f2b(in[(size_t)(r0 + r) * C + c0 + tc]);
  }
  __syncthreads();
  for (int i = 0; i < 16; i++) {
    int r = tr + i * 4;  // row of out tile (= col of in)
    out[(size_t)(c0 + r) * R + r0 + tc] = tile[r][tc];
  }
}

// ------------------------------------------- bf16 transpose (per batch): out[b][c][s] = in[b][s][c]
// in: [B*2048][1024], out: [B*1024][2048]
__global__ __launch_bounds__(256) void transpose_v(const bf16* __restrict__ in,
                                                   bf16* __restrict__ out) {
  __shared__ __align__(16) bf16 tile[64][72];
  const int b = blockIdx.z;
  const int s0 = blockIdx.y * 64, c0 = blockIdx.x * 64;
  const int t = threadIdx.x;
  const int rr = t >> 3, g8 = (t & 7) * 8;
#pragma unroll
  for (int i = 0; i < 2; i++) {
    int s = rr + i * 32;
    *(int4*)&tile[s][g8] = *(const int4*)&in[((size_t)(b * 2048 + s0 + s)) * 1024 + c0 + g8];
  }
  __syncthreads();
#pragma unroll
  for (int i = 0; i < 2; i++) {
    int c = rr + i * 32;
    bf16 tmp[8];
#pragma unroll
    for (int j = 0; j < 8; j++) tmp[j] = tile[g8 + j][c];
    *(int4*)&out[((size_t)(b * 1024 + c0 + c)) * 2048 + s0 + g8] = *(int4*)tmp;
  }
}

// ---------------------------------------------------------------- GEMM  C = A * Bt^T
static __device__ __forceinline__ void store_out(float* p, float v) { *p = v; }
static __device__ __forceinline__ void store_out(bf16* p, float v) { *p = f2b(v); }

// ---------- 128^2-tile kernel (m97 structure) — used for K/V projections (N=1024)
template <typename OutT>
__global__ __launch_bounds__(256) void gemm_bt(const bf16* __restrict__ A,
                                               const bf16* __restrict__ Bt,
                                               OutT* __restrict__ C,
                                               int M, int N, int K) {
  __shared__ __align__(16) bf16 As[128][32];  // unpadded: required by global_load_lds
  __shared__ __align__(16) bf16 Bs[128][32];
  const int t = threadIdx.x;
  const int m0 = blockIdx.y * 128;
  const int n0 = blockIdx.x * 128;
  const int lane = t & 63, wave = t >> 6;
  const int wm = (wave >> 1) * 64, wn = (wave & 1) * 64;
  const int lr = lane & 15, quad = lane >> 4;

  const int srow = wave * 16 + (lane >> 2);
  const int skg = (lane & 3) << 3;
  const bf16* Ap0 = A + (size_t)(m0 + srow) * K + skg;
  const bf16* Ap1 = A + (size_t)(m0 + 64 + srow) * K + skg;
  const bf16* Bp0 = Bt + (size_t)(n0 + srow) * K + skg;
  const bf16* Bp1 = Bt + (size_t)(n0 + 64 + srow) * K + skg;
  bf16* lA0 = &As[wave * 16][0];
  bf16* lA1 = &As[64 + wave * 16][0];
  bf16* lB0 = &Bs[wave * 16][0];
  bf16* lB1 = &Bs[64 + wave * 16][0];

  f32x4 acc[4][4] = {};

  for (int k0 = 0; k0 < K; k0 += 32) {
    async_ld16(Ap0 + k0, lA0);
    async_ld16(Ap1 + k0, lA1);
    async_ld16(Bp0 + k0, lB0);
    async_ld16(Bp1 + k0, lB1);
    __syncthreads();
    bf16x8 a[4], b[4];
#pragma unroll
    for (int i = 0; i < 4; i++) a[i] = *(const bf16x8*)&As[wm + i * 16 + lr][quad * 8];
#pragma unroll
    for (int j = 0; j < 4; j++) b[j] = *(const bf16x8*)&Bs[wn + j * 16 + lr][quad * 8];
#pragma unroll
    for (int i = 0; i < 4; i++)
#pragma unroll
      for (int j = 0; j < 4; j++)
        acc[i][j] = __builtin_amdgcn_mfma_f32_16x16x32_bf16(a[i], b[j], acc[i][j], 0, 0, 0);
    __syncthreads();
  }
#pragma unroll
  for (int i = 0; i < 4; i++) {
    int row = m0 + wm + i * 16 + quad * 4;
#pragma unroll
    for (int j = 0; j < 4; j++) {
      int col = n0 + wn + j * 16 + lr;
#pragma unroll
      for (int r = 0; r < 4; r++)
        store_out(&C[(size_t)(row + r) * N + col], acc[i][j][r]);
    }
  }
}

// ---------- 256^2-tile 8-phase kernel (T2+T3+T4+T5) — used for Q/O projections
// K fixed = 4096. 512 threads = 8 waves (2M x 4N); per-wave output 128x64 as two
// 64-row / 32-col chunks so each phase touches exactly ONE 128-row LDS half of A
// and of B. LDS 128 KB double-buffered; staging via global_load_lds with
// XOR-granule swizzle (g ^= row&7) pre-applied on the GLOBAL source, same XOR on
// ds_read -> 2 lanes/bank (free). Counted vmcnt(4) once per K-tile, never 0 in
// steady state: at each wait the newest 4 loads are exactly the two half-tiles
// (A0/B0 of tile s+2) not needed until the tile after next.
static __device__ __forceinline__ void stage_half(const bf16* __restrict__ base, int r0,
                                                  int kt, int h, bf16* lds_half,
                                                  int wid, int lane) {
#pragma unroll
  for (int rd = 0; rd < 2; rd++) {
    int G = rd * 512 + wid * 64 + lane;   // granule id in the 128x64 half-tile
    int r = G >> 3, gr = G & 7;
    int gs = gr ^ (r & 7);                // pre-swizzled global granule
    async_ld16(base + (size_t)(r0 + h * 128 + r) * 4096 + kt * 64 + gs * 8,
               lds_half + (rd * 512 + wid * 64) * 8);
  }
}

template <typename OutT>
__global__ __launch_bounds__(512, 2) void gemm256(const bf16* __restrict__ A,
                                                  const bf16* __restrict__ Bt,
                                                  OutT* __restrict__ C,
                                                  int M, int N) {
  __shared__ __align__(16) bf16 As[2][256][64];   // 64 KB
  __shared__ __align__(16) bf16 Bs[2][256][64];   // 64 KB
  const int t = threadIdx.x, lane = t & 63, wid = t >> 6;
  const int lr = lane & 15, quad = lane >> 4;
  const int wm = wid >> 2, wn = wid & 3;          // 2 x 4 wave grid

  // XCD-aware bijective swizzle (grid % 8 == 0 here: 256 blocks)
  const int nbx = N >> 8;
  int bid = blockIdx.x;
  int swz = (bid & 7) * ((int)gridDim.x >> 3) + (bid >> 3);
  const int m0 = (swz / nbx) * 256, n0 = (swz % nbx) * 256;

#define A_FRAG(buf, mi, ks)                                                       \
  (*(const bf16x8*)&As[buf][((mi) >> 2) * 128 + wm * 64 + ((mi) & 3) * 16 + lr]   \
        [((((ks) << 2) | quad) ^ (lr & 7)) << 3])
#define B_FRAG(buf, ni, ks)                                                       \
  (*(const bf16x8*)&Bs[buf][((ni) >> 1) * 128 + wn * 32 + ((ni) & 1) * 16 + lr]   \
        [((((ks) << 2) | quad) ^ (lr & 7)) << 3])

  f32x4 acc[8][4] = {};
  bf16x8 areg[4][2], b0[2][2], b1[2][2];
  const int NT = 4096 / 64;  // 64 K-tiles

  // prologue: stage in steady-state issue order
  stage_half(A,  m0, 0, 0, &As[0][0][0],   wid, lane);  // A0(0)
  stage_half(Bt, n0, 0, 0, &Bs[0][0][0],   wid, lane);  // B0(0)
  stage_half(A,  m0, 0, 1, &As[0][128][0], wid, lane);  // A1(0)
  stage_half(Bt, n0, 0, 1, &Bs[0][128][0], wid, lane);  // B1(0)
  stage_half(A,  m0, 1, 0, &As[1][0][0],   wid, lane);  // A0(1)
  stage_half(Bt, n0, 1, 0, &Bs[1][0][0],   wid, lane);  // B1... B0(1)
  asm volatile("s_waitcnt vmcnt(4)" ::: "memory");      // tile 0 fully resident
  __builtin_amdgcn_s_barrier();

  for (int s = 0; s < NT; s++) {
    const int buf = s & 1, nb = buf ^ 1;

    // ---- phase 0: read A-low + B-low; stage A1(s+1); MFMA quadrant (lo,lo)
#pragma unroll
    for (int mi = 0; mi < 4; mi++)
#pragma unroll
      for (int ks = 0; ks < 2; ks++) areg[mi][ks] = A_FRAG(buf, mi, ks);
#pragma unroll
    for (int ni = 0; ni < 2; ni++)
#pragma unroll
      for (int ks = 0; ks < 2; ks++) b0[ni][ks] = B_FRAG(buf, ni, ks);
    if (s + 1 < NT) stage_half(A, m0, s + 1, 1, &As[nb][128][0], wid, lane);
    __builtin_amdgcn_s_barrier();
    __builtin_amdgcn_s_setprio(1);
#pragma unroll
    for (int mi = 0; mi < 4; mi++)
#pragma unroll
      for (int ni = 0; ni < 2; ni++)
#pragma unroll
        for (int ks = 0; ks < 2; ks++)
          acc[mi][ni] = __builtin_amdgcn_mfma_f32_16x16x32_bf16(areg[mi][ks], b0[ni][ks],
                                                                acc[mi][ni], 0, 0, 0);
    __builtin_amdgcn_s_setprio(0);
    __builtin_amdgcn_s_barrier();

    // ---- phase 1: read B-high; stage B1(s+1); MFMA quadrant (lo,hi)
#pragma unroll
    for (int ni = 0; ni < 2; ni++)
#pragma unroll
      for (int ks = 0; ks < 2; ks++) b1[ni][ks] = B_FRAG(buf, ni + 2, ks);
    if (s + 1 < NT) stage_half(Bt, n0, s + 1, 1, &Bs[nb][128][0], wid, lane);
    __builtin_amdgcn_s_barrier();
    __builtin_amdgcn_s_setprio(1);
#pragma unroll
    for (int mi = 0; mi < 4; mi++)
#pragma unroll
      for (int ni = 0; ni < 2; ni++)
#pragma unroll
        for (int ks = 0; ks < 2; ks++)
          acc[mi][ni + 2] = __builtin_amdgcn_mfma_f32_16x16x32_bf16(areg[mi][ks], b1[ni][ks],
                                                                    acc[mi][ni + 2], 0, 0, 0);
    __builtin_amdgcn_s_setprio(0);
    __builtin_amdgcn_s_barrier();

    // ---- phase 2: read A-high; stage A0(s+2) (slot last read in phase 0); MFMA (hi,lo)
#pragma unroll
    for (int mi = 0; mi < 4; mi++)
#pragma unroll
      for (int ks = 0; ks < 2; ks++) areg[mi][ks] = A_FRAG(buf, mi + 4, ks);
    if (s + 2 < NT) stage_half(A, m0, s + 2, 0, &As[buf][0][0], wid, lane);
    __builtin_amdgcn_s_barrier();
    __builtin_amdgcn_s_setprio(1);
#pragma unroll
    for (int mi = 0; mi < 4; mi++)
#pragma unroll
      for (int ni = 0; ni < 2; ni++)
#pragma unroll
        for (int ks = 0; ks < 2; ks++)
          acc[mi + 4][ni] = __builtin_amdgcn_mfma_f32_16x16x32_bf16(areg[mi][ks], b0[ni][ks],
                                                                    acc[mi + 4][ni], 0, 0, 0);
    __builtin_amdgcn_s_setprio(0);
    __builtin_amdgcn_s_barrier();

    // ---- phase 3: stage B0(s+2); MFMA (hi,hi); counted vmcnt; tile boundary
    if (s + 2 < NT) stage_half(Bt, n0, s + 2, 0, &Bs[buf][0][0], wid, lane);
    __builtin_amdgcn_s_barrier();
    __builtin_amdgcn_s_setprio(1);
#pragma unroll
    for (int mi = 0; mi < 4; mi++)
#pragma unroll
      for (int ni = 0; ni < 2; ni++)
#pragma unroll
        for (int ks = 0; ks < 2; ks++)
          acc[mi + 4][ni + 2] = __builtin_amdgcn_mfma_f32_16x16x32_bf16(areg[mi][ks], b1[ni][ks],
                                                                        acc[mi + 4][ni + 2], 0, 0, 0);
    __builtin_amdgcn_s_setprio(0);
    if (s + 2 < NT) {
      asm volatile("s_waitcnt vmcnt(4)" ::: "memory");   // newest 4 = A0/B0(s+2)
    } else if (s + 1 < NT) {
      asm volatile("s_waitcnt vmcnt(0)" ::: "memory");   // epilogue: drain for tile s+1
    }
    __builtin_amdgcn_s_barrier();
  }
#undef A_FRAG
#undef B_FRAG

  // epilogue: C row = quad*4+r within fragment, col = lr (verified layout)
#pragma unroll
  for (int mi = 0; mi < 8; mi++) {
    int row = m0 + (mi >> 2) * 128 + wm * 64 + (mi & 3) * 16 + quad * 4;
#pragma unroll
    for (int ni = 0; ni < 4; ni++) {
      int col = n0 + (ni >> 1) * 128 + wn * 32 + (ni & 1) * 16 + lr;
#pragma unroll
      for (int r = 0; r < 4; r++)
        store_out(&C[(size_t)(row + r) * N + col], acc[mi][ni][r]);
    }
  }
}

// ---------------------------------------------------------------- RoPE (in-place) + scale
__global__ __launch_bounds__(256) void rope_kernel(bf16* __restrict__ X, int lh, float scale) {
  int idx = blockIdx.x * 256 + threadIdx.x;
  int d = idx & 63;
  int rest = idx >> 6;
  int h = rest & ((1 << lh) - 1);
  int tok = rest >> lh;
  float ang = (float)(tok & (SEQ - 1)) * exp2f((float)d * -0.2076205059304602f);  // log2(1e4)/64
  float sn, cs;
  sincosf(ang, &sn, &cs);
  bf16* p = X + (((size_t)tok << lh) + h) * HEAD_DIM + d;
  float x0 = b2f(p[0]), x1 = b2f(p[64]);
  p[0]  = f2b((x0 * cs - x1 * sn) * scale);
  p[64] = f2b((x1 * cs + x0 * sn) * scale);
}

// ---------------------------------------------------------------- flash attention (causal, GQA)
// Round-1 verified version: QBLK=128 (8 waves x 16 q rows), KVBLK=64, double-
// buffered global_load_lds staging with XOR-granule swizzle, exp2-domain softmax.
static __device__ __forceinline__ void stage_kv(const bf16* kbase, const bf16* vtbase,
                                                bf16* ksb, bf16* vtb,
                                                int jt, int w, int lane) {
  // K tile: 64 rows x 256B = 1024 granules of 16B. LDS(r,g) <- global(r, g^(r&7))
#pragma unroll
  for (int rd = 0; rd < 2; rd++) {
    int G = rd * 512 + w * 64 + lane;
    int r = G >> 4;
    int gs = (G & 15) ^ (r & 7);
    async_ld16(kbase + (size_t)(jt * 64 + r) * 1024 + gs * 8, ksb + (rd * 512 + w * 64) * 8);
  }
  // V^T tile: 128 rows x 128B = 1024 granules. LDS(d,g) <- global(d, g^(d&7))
#pragma unroll
  for (int rd = 0; rd < 2; rd++) {
    int G = rd * 512 + w * 64 + lane;
    int d = G >> 3;
    int gs = (G & 7) ^ (d & 7);
    async_ld16(vtbase + (size_t)d * 2048 + jt * 64 + gs * 8, vtb + (rd * 512 + w * 64) * 8);
  }
}

__global__ __launch_bounds__(512) void flash_attn(const bf16* __restrict__ Q,
                                                  const bf16* __restrict__ K,
                                                  const bf16* __restrict__ VT,
                                                  bf16* __restrict__ O) {
  __shared__ __align__(16) bf16 Ks[2][64][128];   // 2 x 16 KB
  __shared__ __align__(16) bf16 Vt[2][128][64];   // 2 x 16 KB

  const int qb = (int)gridDim.x - 1 - (int)blockIdx.x;  // longest blocks launch first
  const int h = blockIdx.y, b = blockIdx.z;
  const int kvh = h >> 2;  // GROUP = 4
  const int t = threadIdx.x, lane = t & 63, w = t >> 6;  // w in 0..7
  const int lr = lane & 15, quad = lane >> 4;

  const bf16* kbase = K + ((size_t)(b * SEQ) * N_KV + kvh) * HEAD_DIM;
  const bf16* vtbase = VT + (size_t)(b * 1024 + kvh * 128) * 2048;

  // per-lane swizzled LDS read offsets (elements). r&7 == lr&7 for all rows read.
  int koff[4], voff[4];
#pragma unroll
  for (int ks = 0; ks < 4; ks++) koff[ks] = (((ks << 2) + quad) ^ (lr & 7)) << 3;
#pragma unroll
  for (int j = 0; j < 4; j++)
    voff[j] = (((((j << 1) + (quad >> 1)) ^ (lr & 7)) << 3) + ((quad & 1) << 2));

  // this lane's q token (each lane owns exactly one q row of the wave's 16)
  const int tok = b * SEQ + qb * 128 + w * 16 + lr;

  // Q fragments straight from global (post-RoPE): B-frag n=lr, k = ks*32+quad*8+j
  bf16x8 qf[4];
  {
    const bf16* qrow = Q + (size_t)tok * D_MODEL + h * HEAD_DIM + quad * 8;
#pragma unroll
    for (int ks = 0; ks < 4; ks++) qf[ks] = *(const bf16x8*)(qrow + ks * 32);
  }

  f32x4 o_acc[8] = {};          // O^T: d = n*16 + quad*4 + r, q = lr
  float m_i = -1e30f, l_i = 0.f;

  const int nt = 2 * qb + 2;    // kv tiles covering rows [0, qb*128+128)
  bf16* ksc = &Ks[0][0][0]; bf16* vtc = &Vt[0][0][0];
  bf16* ksn = &Ks[1][0][0]; bf16* vtn = &Vt[1][0][0];

  stage_kv(kbase, vtbase, ksc, vtc, 0, w, lane);
  __syncthreads();  // implicit vmcnt(0) before barrier completes the DMA

  for (int jt = 0; jt < nt; jt++) {
    // issue next tile's DMA first: latency hides under this tile's compute
    if (jt + 1 < nt) stage_kv(kbase, vtbase, ksn, vtn, jt + 1, w, lane);

    // waves whose 16 q rows are entirely above this kv tile skip compute
    // (wave-uniform: only possible on the final tile)
    if (jt * 64 <= qb * 128 + w * 16 + 15) {
      // S^T = K * Q^T : 4 sk-tiles of 16; C-layout: sk = j*16+quad*4+r, q = lr
      f32x4 s_acc[4] = {};
#pragma unroll
      for (int j = 0; j < 4; j++) {
        const bf16* krow = ksc + (j * 16 + lr) * 128;
#pragma unroll
        for (int ks = 0; ks < 4; ks++) {
          bf16x8 kf = *(const bf16x8*)(krow + koff[ks]);
          s_acc[j] = __builtin_amdgcn_mfma_f32_16x16x32_bf16(kf, qf[ks], s_acc[j], 0, 0, 0);
        }
      }

      // causal mask (only the last two tiles can touch the diagonal)
      if (jt >= 2 * qb) {
        int sq = w * 16 + lr;
        int kb0 = jt * 64 - qb * 128;
#pragma unroll
        for (int j = 0; j < 4; j++)
#pragma unroll
          for (int r = 0; r < 4; r++)
            if (kb0 + j * 16 + quad * 4 + r > sq) s_acc[j][r] = -1e30f;
      }

      // online softmax in exp2 domain — per-lane scalars (lane owns q row lr)
      float mx = -1e30f;
#pragma unroll
      for (int j = 0; j < 4; j++)
#pragma unroll
        for (int r = 0; r < 4; r++) mx = fmaxf(mx, s_acc[j][r]);
      mx = fmaxf(mx, __shfl_xor(mx, 16));
      mx = fmaxf(mx, __shfl_xor(mx, 32));
      float mnew = fmaxf(m_i, mx);
      float alpha = exp2f(m_i - mnew);
      m_i = mnew;

      float p[4][4];
      float sum = 0.f;
#pragma unroll
      for (int j = 0; j < 4; j++)
#pragma unroll
        for (int r = 0; r < 4; r++) {
          p[j][r] = exp2f(s_acc[j][r] - mnew);
          sum += p[j][r];
        }
      sum += __shfl_xor(sum, 16);
      sum += __shfl_xor(sum, 32);
      l_i = l_i * alpha + sum;

#pragma unroll
      for (int n = 0; n < 8; n++)
#pragma unroll
        for (int r = 0; r < 4; r++) o_acc[n][r] *= alpha;

      // pack P into 16x16x16 B-fragments (k = quad*4 + r) — in registers, no LDS
      bf16x4 pf[4];
#pragma unroll
      for (int j = 0; j < 4; j++) {
        pf[j][0] = f2bs(p[j][0]); pf[j][1] = f2bs(p[j][1]);
        pf[j][2] = f2bs(p[j][2]); pf[j][3] = f2bs(p[j][3]);
      }

      // O^T += V^T * P^T  (K=16 per mfma, 4 sk-chunks x 8 d-tiles)
#pragma unroll
      for (int j = 0; j < 4; j++)
#pragma unroll
        for (int n = 0; n < 8; n++) {
          bf16x4 vf = *(const bf16x4*)(vtc + (n * 16 + lr) * 64 + voff[j]);
          o_acc[n] = __builtin_amdgcn_mfma_f32_16x16x16bf16_1k(vf, pf[j], o_acc[n], 0, 0, 0);
        }
    }

    __syncthreads();  // readers done with cur + this wave's DMA into next drained
    bf16* tp;
    tp = ksc; ksc = ksn; ksn = tp;
    tp = vtc; vtc = vtn; vtn = tp;
  }

  // epilogue: O[tok][h*128 + d] = o_acc / l ; d = n*16 + quad*4 + r (4 consecutive)
  {
    float inv_l = 1.f / l_i;
    bf16* obase = O + (size_t)tok * D_MODEL + h * HEAD_DIM + quad * 4;
#pragma unroll
    for (int n = 0; n < 8; n++) {
      bf16x4 ov;
      ov[0] = f2bs(o_acc[n][0] * inv_l); ov[1] = f2bs(o_acc[n][1] * inv_l);
      ov[2] = f2bs(o_acc[n][2] * inv_l); ov[3] = f2bs(o_acc[n][3] * inv_l);
      *(bf16x4*)(obase + n * 16) = ov;
    }
  }
}

// ---------------------------------------------------------------- launcher
extern "C" void kernel_launch(void* const* d_in, const int* in_sizes, int n_in,
                              void* d_out, int out_size, void* d_ws, size_t ws_size,
                              hipStream_t stream) {
  const float* x  = (const float*)d_in[0];
  // d_in[1] = mask: exactly causal (triu k=1) -> hard-coded in flash kernel
  const float* Wq = (const float*)d_in[2];
  const float* Wk = (const float*)d_in[3];
  const float* Wv = (const float*)d_in[4];
  const float* Wo = (const float*)d_in[5];
  float* out = (float*)d_out;

  char* ws = (char*)d_ws;
  const size_t MB = 1024 * 1024;
  bf16* xb  = (bf16*)(ws + 0);         // 32 MB  [4096][4096]
  bf16* WqT = (bf16*)(ws + 32 * MB);   // 32 MB  (dead after Q gemm; reused as Ob)
  bf16* WkT = (bf16*)(ws + 64 * MB);   // 8 MB   [1024][4096]
  bf16* WvT = (bf16*)(ws + 72 * MB);   // 8 MB
  bf16* WoT = (bf16*)(ws + 80 * MB);   // 32 MB
  bf16* Qb  = (bf16*)(ws + 112 * MB);  // 32 MB  [4096][4096]
  bf16* Kb  = (bf16*)(ws + 144 * MB);  // 8 MB   [4096][1024]
  bf16* Vb  = (bf16*)(ws + 152 * MB);  // 8 MB
  bf16* VTb = (bf16*)(ws + 160 * MB);  // 8 MB   [B*1024][2048]
  bf16* Ob  = WqT;                     // alias: WqT unused after Q projection

  // 1. cast activations
  cast_f32_to_bf16<<<dim3(NTOK * D_MODEL / 4 / 256), 256, 0, stream>>>(x, xb, NTOK * D_MODEL / 4);
  // 2. transpose-cast weights to [N][K] bf16
  transpose_cast<<<dim3(D_MODEL / 64, D_MODEL / 64), 256, 0, stream>>>(Wq, WqT, D_MODEL, D_MODEL);
  transpose_cast<<<dim3(1024 / 64, D_MODEL / 64), 256, 0, stream>>>(Wk, WkT, D_MODEL, 1024);
  transpose_cast<<<dim3(1024 / 64, D_MODEL / 64), 256, 0, stream>>>(Wv, WvT, D_MODEL, 1024);
  transpose_cast<<<dim3(D_MODEL / 64, D_MODEL / 64), 256, 0, stream>>>(Wo, WoT, D_MODEL, D_MODEL);
  // 3. projections: Q via 256^2 8-phase; K/V via 128^2 (N=1024 -> 256 blocks)
  gemm256<bf16><<<dim3(256), 512, 0, stream>>>(xb, WqT, Qb, NTOK, D_MODEL);
  gemm_bt<bf16><<<dim3(1024 / 128, NTOK / 128), 256, 0, stream>>>(xb, WkT, Kb, NTOK, 1024, D_MODEL);
  gemm_bt<bf16><<<dim3(1024 / 128, NTOK / 128), 256, 0, stream>>>(xb, WvT, Vb, NTOK, 1024, D_MODEL);
  // 4. RoPE; Q scale = head_dim^-0.5 * log2(e)  (softmax runs in exp2 domain)
  rope_kernel<<<dim3(NTOK * N_HEADS * 64 / 256), 256, 0, stream>>>(Qb, 5, 0.12751741737890f);
  rope_kernel<<<dim3(NTOK * N_KV * 64 / 256), 256, 0, stream>>>(Kb, 3, 1.0f);
  // 5. pre-transpose V per batch: VT[b][c][s]
  transpose_v<<<dim3(1024 / 64, SEQ / 64, BATCH), 256, 0, stream>>>(Vb, VTb);
  // 6. attention (QBLK=128, 8 waves, double-buffered async staging)
  flash_attn<<<dim3(SEQ / 128, N_HEADS, BATCH), 512, 0, stream>>>(Qb, Kb, VTb, Ob);
  // 7. output projection (fp32 out) via 256^2 8-phase
  gemm256<float><<<dim3(256), 512, 0, stream>>>(Ob, WoT, out, NTOK, D_MODEL);
}

// Round 4
// 822.062 us; speedup vs baseline: 1.8977x; 1.1125x over previous
//
#include <hip/hip_runtime.h>
#include <hip/hip_bf16.h>

typedef __hip_bfloat16 bf16;
typedef float f32x4 __attribute__((ext_vector_type(4)));
typedef short bf16x8 __attribute__((ext_vector_type(8)));  // 8 bf16 in 4 VGPRs
typedef short bf16x4 __attribute__((ext_vector_type(4)));  // 4 bf16 in 2 VGPRs

#define D_MODEL 4096
#define N_HEADS 32
#define N_KV 8
#define HEAD_DIM 128
#define SEQ 2048
#define BATCH 2
#define NTOK (BATCH * SEQ)  // 4096
#define KVSTRIDE 2048       // fused K|V projection row stride

static __device__ __forceinline__ float b2f(bf16 v) { return __bfloat162float(v); }
static __device__ __forceinline__ bf16 f2b(float v) { return __float2bfloat16(v); }
static __device__ __forceinline__ short f2bs(float v) {
  union { bf16 b; short s; } u; u.b = f2b(v); return u.s;
}

// async global->LDS, 16B per lane; lds dest must be wave-uniform base (+ lane*16B implicit)
static __device__ __forceinline__ void async_ld16(const bf16* g, bf16* l) {
  __builtin_amdgcn_global_load_lds(
      (const __attribute__((address_space(1))) void*)g,
      (__attribute__((address_space(3))) void*)l, 16, 0, 0);
}

// ---------------------------------------------------------------- cast x -> bf16
__global__ __launch_bounds__(256) void cast_f32_to_bf16(const float* __restrict__ in,
                                                        bf16* __restrict__ out, int n4) {
  int i = blockIdx.x * 256 + threadIdx.x;
  if (i >= n4) return;
  float4 v = ((const float4*)in)[i];
  union { ushort4 u; bf16 b[4]; } o;
  o.b[0] = f2b(v.x); o.b[1] = f2b(v.y); o.b[2] = f2b(v.z); o.b[3] = f2b(v.w);
  ((ushort4*)out)[i] = o.u;
}

// ------------------------------------------- transpose+cast: in[R][C] f32 -> out[C][R] bf16
__global__ __launch_bounds__(256) void transpose_cast(const float* __restrict__ in,
                                                      bf16* __restrict__ out, int R, int C) {
  __shared__ bf16 tile[64][65];
  const int c0 = blockIdx.x * 64;
  const int r0 = blockIdx.y * 64;
  const int t = threadIdx.x;
  const int tc = t & 63, tr = t >> 6;  // 4 rows per pass
  for (int i = 0; i < 16; i++) {
    int r = tr + i * 4;
    tile[tc][r] = f2b(in[(size_t)(r0 + r) * C + c0 + tc]);
  }
  __syncthreads();
  for (int i = 0; i < 16; i++) {
    int r = tr + i * 4;  // row of out tile (= col of in)
    out[(size_t)(c0 + r) * R + r0 + tc] = tile[r][tc];
  }
}

// ------------------------------------------- bf16 transpose (per batch), V half of fused KV:
// in KV[B*2048][2048] (V at col offset 1024): out[b][c][s] = KV[b*2048+s][1024+c]
__global__ __launch_bounds__(256) void transpose_v(const bf16* __restrict__ in,
                                                   bf16* __restrict__ out) {
  __shared__ __align__(16) bf16 tile[64][72];
  const int b = blockIdx.z;
  const int s0 = blockIdx.y * 64, c0 = blockIdx.x * 64;
  const int t = threadIdx.x;
  const int rr = t >> 3, g8 = (t & 7) * 8;
#pragma unroll
  for (int i = 0; i < 2; i++) {
    int s = rr + i * 32;
    *(int4*)&tile[s][g8] =
        *(const int4*)&in[((size_t)(b * 2048 + s0 + s)) * KVSTRIDE + 1024 + c0 + g8];
  }
  __syncthreads();
#pragma unroll
  for (int i = 0; i < 2; i++) {
    int c = rr + i * 32;
    bf16 tmp[8];
#pragma unroll
    for (int j = 0; j < 8; j++) tmp[j] = tile[g8 + j][c];
    *(int4*)&out[((size_t)(b * 1024 + c0 + c)) * 2048 + s0 + g8] = *(int4*)tmp;
  }
}

// ---------------------------------------------------------------- GEMM  C = A * Bt^T
static __device__ __forceinline__ void store_out(float* p, float v) { *p = v; }
static __device__ __forceinline__ void store_out(bf16* p, float v) { *p = f2b(v); }

// ---------- 128^2-tile kernel (m97 structure) — used for the fused KV projection (N=2048)
template <typename OutT>
__global__ __launch_bounds__(256) void gemm_bt(const bf16* __restrict__ A,
                                               const bf16* __restrict__ Bt,
                                               OutT* __restrict__ C,
                                               int M, int N, int K) {
  __shared__ __align__(16) bf16 As[128][32];  // unpadded: required by global_load_lds
  __shared__ __align__(16) bf16 Bs[128][32];
  const int t = threadIdx.x;
  const int m0 = blockIdx.y * 128;
  const int n0 = blockIdx.x * 128;
  const int lane = t & 63, wave = t >> 6;
  const int wm = (wave >> 1) * 64, wn = (wave & 1) * 64;
  const int lr = lane & 15, quad = lane >> 4;

  const int srow = wave * 16 + (lane >> 2);
  const int skg = (lane & 3) << 3;
  const bf16* Ap0 = A + (size_t)(m0 + srow) * K + skg;
  const bf16* Ap1 = A + (size_t)(m0 + 64 + srow) * K + skg;
  const bf16* Bp0 = Bt + (size_t)(n0 + srow) * K + skg;
  const bf16* Bp1 = Bt + (size_t)(n0 + 64 + srow) * K + skg;
  bf16* lA0 = &As[wave * 16][0];
  bf16* lA1 = &As[64 + wave * 16][0];
  bf16* lB0 = &Bs[wave * 16][0];
  bf16* lB1 = &Bs[64 + wave * 16][0];

  f32x4 acc[4][4] = {};

  for (int k0 = 0; k0 < K; k0 += 32) {
    async_ld16(Ap0 + k0, lA0);
    async_ld16(Ap1 + k0, lA1);
    async_ld16(Bp0 + k0, lB0);
    async_ld16(Bp1 + k0, lB1);
    __syncthreads();
    bf16x8 a[4], b[4];
#pragma unroll
    for (int i = 0; i < 4; i++) a[i] = *(const bf16x8*)&As[wm + i * 16 + lr][quad * 8];
#pragma unroll
    for (int j = 0; j < 4; j++) b[j] = *(const bf16x8*)&Bs[wn + j * 16 + lr][quad * 8];
#pragma unroll
    for (int i = 0; i < 4; i++)
#pragma unroll
      for (int j = 0; j < 4; j++)
        acc[i][j] = __builtin_amdgcn_mfma_f32_16x16x32_bf16(a[i], b[j], acc[i][j], 0, 0, 0);
    __syncthreads();
  }
#pragma unroll
  for (int i = 0; i < 4; i++) {
    int row = m0 + wm + i * 16 + quad * 4;
#pragma unroll
    for (int j = 0; j < 4; j++) {
      int col = n0 + wn + j * 16 + lr;
#pragma unroll
      for (int r = 0; r < 4; r++)
        store_out(&C[(size_t)(row + r) * N + col], acc[i][j][r]);
    }
  }
}

// ---------- 256^2-tile 8-phase kernel (T2+T3+T4+T5) — used for Q/O projections
// K fixed = 4096. 512 threads = 8 waves (2M x 4N); per-wave output 128x64 as two
// 64-row / 32-col chunks so each phase touches exactly ONE 128-row LDS half of A
// and of B. LDS 128 KB double-buffered; staging via global_load_lds with
// XOR-granule swizzle (g ^= row&7) pre-applied on the GLOBAL source, same XOR on
// ds_read -> 2 lanes/bank (free). Counted vmcnt(4) once per K-tile, never 0 in
// steady state.
static __device__ __forceinline__ void stage_half(const bf16* __restrict__ base, int r0,
                                                  int kt, int h, bf16* lds_half,
                                                  int wid, int lane) {
#pragma unroll
  for (int rd = 0; rd < 2; rd++) {
    int G = rd * 512 + wid * 64 + lane;   // granule id in the 128x64 half-tile
    int r = G >> 3, gr = G & 7;
    int gs = gr ^ (r & 7);                // pre-swizzled global granule
    async_ld16(base + (size_t)(r0 + h * 128 + r) * 4096 + kt * 64 + gs * 8,
               lds_half + (rd * 512 + wid * 64) * 8);
  }
}

template <typename OutT>
__global__ __launch_bounds__(512, 2) void gemm256(const bf16* __restrict__ A,
                                                  const bf16* __restrict__ Bt,
                                                  OutT* __restrict__ C,
                                                  int M, int N) {
  __shared__ __align__(16) bf16 As[2][256][64];   // 64 KB
  __shared__ __align__(16) bf16 Bs[2][256][64];   // 64 KB
  const int t = threadIdx.x, lane = t & 63, wid = t >> 6;
  const int lr = lane & 15, quad = lane >> 4;
  const int wm = wid >> 2, wn = wid & 3;          // 2 x 4 wave grid

  // XCD-aware bijective swizzle (grid % 8 == 0 here: 256 blocks)
  const int nbx = N >> 8;
  int bid = blockIdx.x;
  int swz = (bid & 7) * ((int)gridDim.x >> 3) + (bid >> 3);
  const int m0 = (swz / nbx) * 256, n0 = (swz % nbx) * 256;

#define A_FRAG(buf, mi, ks)                                                       \
  (*(const bf16x8*)&As[buf][((mi) >> 2) * 128 + wm * 64 + ((mi) & 3) * 16 + lr]   \
        [((((ks) << 2) | quad) ^ (lr & 7)) << 3])
#define B_FRAG(buf, ni, ks)                                                       \
  (*(const bf16x8*)&Bs[buf][((ni) >> 1) * 128 + wn * 32 + ((ni) & 1) * 16 + lr]   \
        [((((ks) << 2) | quad) ^ (lr & 7)) << 3])

  f32x4 acc[8][4] = {};
  bf16x8 areg[4][2], b0[2][2], b1[2][2];
  const int NT = 4096 / 64;  // 64 K-tiles

  // prologue: stage in steady-state issue order
  stage_half(A,  m0, 0, 0, &As[0][0][0],   wid, lane);  // A0(0)
  stage_half(Bt, n0, 0, 0, &Bs[0][0][0],   wid, lane);  // B0(0)
  stage_half(A,  m0, 0, 1, &As[0][128][0], wid, lane);  // A1(0)
  stage_half(Bt, n0, 0, 1, &Bs[0][128][0], wid, lane);  // B1(0)
  stage_half(A,  m0, 1, 0, &As[1][0][0],   wid, lane);  // A0(1)
  stage_half(Bt, n0, 1, 0, &Bs[1][0][0],   wid, lane);  // B0(1)
  asm volatile("s_waitcnt vmcnt(4)" ::: "memory");      // tile 0 fully resident
  __builtin_amdgcn_s_barrier();

  for (int s = 0; s < NT; s++) {
    const int buf = s & 1, nb = buf ^ 1;

    // ---- phase 0: read A-low + B-low; stage A1(s+1); MFMA quadrant (lo,lo)
#pragma unroll
    for (int mi = 0; mi < 4; mi++)
#pragma unroll
      for (int ks = 0; ks < 2; ks++) areg[mi][ks] = A_FRAG(buf, mi, ks);
#pragma unroll
    for (int ni = 0; ni < 2; ni++)
#pragma unroll
      for (int ks = 0; ks < 2; ks++) b0[ni][ks] = B_FRAG(buf, ni, ks);
    if (s + 1 < NT) stage_half(A, m0, s + 1, 1, &As[nb][128][0], wid, lane);
    __builtin_amdgcn_s_barrier();
    __builtin_amdgcn_s_setprio(1);
#pragma unroll
    for (int mi = 0; mi < 4; mi++)
#pragma unroll
      for (int ni = 0; ni < 2; ni++)
#pragma unroll
        for (int ks = 0; ks < 2; ks++)
          acc[mi][ni] = __builtin_amdgcn_mfma_f32_16x16x32_bf16(areg[mi][ks], b0[ni][ks],
                                                                acc[mi][ni], 0, 0, 0);
    __builtin_amdgcn_s_setprio(0);
    __builtin_amdgcn_s_barrier();

    // ---- phase 1: read B-high; stage B1(s+1); MFMA quadrant (lo,hi)
#pragma unroll
    for (int ni = 0; ni < 2; ni++)
#pragma unroll
      for (int ks = 0; ks < 2; ks++) b1[ni][ks] = B_FRAG(buf, ni + 2, ks);
    if (s + 1 < NT) stage_half(Bt, n0, s + 1, 1, &Bs[nb][128][0], wid, lane);
    __builtin_amdgcn_s_barrier();
    __builtin_amdgcn_s_setprio(1);
#pragma unroll
    for (int mi = 0; mi < 4; mi++)
#pragma unroll
      for (int ni = 0; ni < 2; ni++)
#pragma unroll
        for (int ks = 0; ks < 2; ks++)
          acc[mi][ni + 2] = __builtin_amdgcn_mfma_f32_16x16x32_bf16(areg[mi][ks], b1[ni][ks],
                                                                    acc[mi][ni + 2], 0, 0, 0);
    __builtin_amdgcn_s_setprio(0);
    __builtin_amdgcn_s_barrier();

    // ---- phase 2: read A-high; stage A0(s+2) (slot last read in phase 0); MFMA (hi,lo)
#pragma unroll
    for (int mi = 0; mi < 4; mi++)
#pragma unroll
      for (int ks = 0; ks < 2; ks++) areg[mi][ks] = A_FRAG(buf, mi + 4, ks);
    if (s + 2 < NT) stage_half(A, m0, s + 2, 0, &As[buf][0][0], wid, lane);
    __builtin_amdgcn_s_barrier();
    __builtin_amdgcn_s_setprio(1);
#pragma unroll
    for (int mi = 0; mi < 4; mi++)
#pragma unroll
      for (int ni = 0; ni < 2; ni++)
#pragma unroll
        for (int ks = 0; ks < 2; ks++)
          acc[mi + 4][ni] = __builtin_amdgcn_mfma_f32_16x16x32_bf16(areg[mi][ks], b0[ni][ks],
                                                                    acc[mi + 4][ni], 0, 0, 0);
    __builtin_amdgcn_s_setprio(0);
    __builtin_amdgcn_s_barrier();

    // ---- phase 3: stage B0(s+2); MFMA (hi,hi); counted vmcnt; tile boundary
    if (s + 2 < NT) stage_half(Bt, n0, s + 2, 0, &Bs[buf][0][0], wid, lane);
    __builtin_amdgcn_s_barrier();
    __builtin_amdgcn_s_setprio(1);
#pragma unroll
    for (int mi = 0; mi < 4; mi++)
#pragma unroll
      for (int ni = 0; ni < 2; ni++)
#pragma unroll
        for (int ks = 0; ks < 2; ks++)
          acc[mi + 4][ni + 2] = __builtin_amdgcn_mfma_f32_16x16x32_bf16(areg[mi][ks], b1[ni][ks],
                                                                        acc[mi + 4][ni + 2], 0, 0, 0);
    __builtin_amdgcn_s_setprio(0);
    if (s + 2 < NT) {
      asm volatile("s_waitcnt vmcnt(4)" ::: "memory");   // newest 4 = A0/B0(s+2)
    } else if (s + 1 < NT) {
      asm volatile("s_waitcnt vmcnt(0)" ::: "memory");   // epilogue: drain for tile s+1
    }
    __builtin_amdgcn_s_barrier();
  }
#undef A_FRAG
#undef B_FRAG

  // epilogue: C row = quad*4+r within fragment, col = lr (verified layout)
#pragma unroll
  for (int mi = 0; mi < 8; mi++) {
    int row = m0 + (mi >> 2) * 128 + wm * 64 + (mi & 3) * 16 + quad * 4;
#pragma unroll
    for (int ni = 0; ni < 4; ni++) {
      int col = n0 + (ni >> 1) * 128 + wn * 32 + (ni & 1) * 16 + lr;
#pragma unroll
      for (int r = 0; r < 4; r++)
        store_out(&C[(size_t)(row + r) * N + col], acc[mi][ni][r]);
    }
  }
}

// ---------------------------------------------------------------- RoPE (in-place) + scale
// X row layout: token row stride = 1<<lrs elems, head h at h*128, 1<<lh heads roped.
__global__ __launch_bounds__(256) void rope_kernel(bf16* __restrict__ X, int lh, int lrs,
                                                   float scale) {
  int idx = blockIdx.x * 256 + threadIdx.x;
  int d = idx & 63;
  int rest = idx >> 6;
  int h = rest & ((1 << lh) - 1);
  int tok = rest >> lh;
  float ang = (float)(tok & (SEQ - 1)) * exp2f((float)d * -0.2076205059304602f);  // log2(1e4)/64
  float sn, cs;
  sincosf(ang, &sn, &cs);
  bf16* p = X + ((size_t)tok << lrs) + (h << 7) + d;
  float x0 = b2f(p[0]), x1 = b2f(p[64]);
  p[0]  = f2b((x0 * cs - x1 * sn) * scale);
  p[64] = f2b((x1 * cs + x0 * sn) * scale);
}

// ---------------------------------------------------------------- flash attention (causal, GQA)
// QBLK=128 (8 waves x 16 q rows), KVBLK=64, double-buffered global_load_lds
// staging with XOR-granule swizzle, exp2-domain softmax, T13 defer-max, T5 setprio.
// K now lives in the fused KV buffer (row stride KVSTRIDE=2048, K at col 0).
static __device__ __forceinline__ void stage_kv(const bf16* kbase, const bf16* vtbase,
                                                bf16* ksb, bf16* vtb,
                                                int jt, int w, int lane) {
  // K tile: 64 rows x 256B = 1024 granules of 16B. LDS(r,g) <- global(r, g^(r&7))
#pragma unroll
  for (int rd = 0; rd < 2; rd++) {
    int G = rd * 512 + w * 64 + lane;
    int r = G >> 4;
    int gs = (G & 15) ^ (r & 7);
    async_ld16(kbase + (size_t)(jt * 64 + r) * KVSTRIDE + gs * 8,
               ksb + (rd * 512 + w * 64) * 8);
  }
  // V^T tile: 128 rows x 128B = 1024 granules. LDS(d,g) <- global(d, g^(d&7))
#pragma unroll
  for (int rd = 0; rd < 2; rd++) {
    int G = rd * 512 + w * 64 + lane;
    int d = G >> 3;
    int gs = (G & 7) ^ (d & 7);
    async_ld16(vtbase + (size_t)d * 2048 + jt * 64 + gs * 8, vtb + (rd * 512 + w * 64) * 8);
  }
}

__global__ __launch_bounds__(512) void flash_attn(const bf16* __restrict__ Q,
                                                  const bf16* __restrict__ KV,
                                                  const bf16* __restrict__ VT,
                                                  bf16* __restrict__ O) {
  __shared__ __align__(16) bf16 Ks[2][64][128];   // 2 x 16 KB
  __shared__ __align__(16) bf16 Vt[2][128][64];   // 2 x 16 KB

  const int qb = (int)gridDim.x - 1 - (int)blockIdx.x;  // longest blocks launch first
  const int h = blockIdx.y, b = blockIdx.z;
  const int kvh = h >> 2;  // GROUP = 4
  const int t = threadIdx.x, lane = t & 63, w = t >> 6;  // w in 0..7
  const int lr = lane & 15, quad = lane >> 4;

  const bf16* kbase = KV + (size_t)(b * SEQ) * KVSTRIDE + kvh * HEAD_DIM;
  const bf16* vtbase = VT + (size_t)(b * 1024 + kvh * 128) * 2048;

  // per-lane swizzled LDS read offsets (elements). r&7 == lr&7 for all rows read.
  int koff[4], voff[4];
#pragma unroll
  for (int ks = 0; ks < 4; ks++) koff[ks] = (((ks << 2) + quad) ^ (lr & 7)) << 3;
#pragma unroll
  for (int j = 0; j < 4; j++)
    voff[j] = (((((j << 1) + (quad >> 1)) ^ (lr & 7)) << 3) + ((quad & 1) << 2));

  // this lane's q token (each lane owns exactly one q row of the wave's 16)
  const int tok = b * SEQ + qb * 128 + w * 16 + lr;

  // Q fragments straight from global (post-RoPE): B-frag n=lr, k = ks*32+quad*8+j
  bf16x8 qf[4];
  {
    const bf16* qrow = Q + (size_t)tok * D_MODEL + h * HEAD_DIM + quad * 8;
#pragma unroll
    for (int ks = 0; ks < 4; ks++) qf[ks] = *(const bf16x8*)(qrow + ks * 32);
  }

  f32x4 o_acc[8] = {};          // O^T: d = n*16 + quad*4 + r, q = lr
  float m_i = -1e30f, l_i = 0.f;

  const int nt = 2 * qb + 2;    // kv tiles covering rows [0, qb*128+128)
  bf16* ksc = &Ks[0][0][0]; bf16* vtc = &Vt[0][0][0];
  bf16* ksn = &Ks[1][0][0]; bf16* vtn = &Vt[1][0][0];

  stage_kv(kbase, vtbase, ksc, vtc, 0, w, lane);
  __syncthreads();  // implicit vmcnt(0) before barrier completes the DMA

  for (int jt = 0; jt < nt; jt++) {
    // issue next tile's DMA first: latency hides under this tile's compute
    if (jt + 1 < nt) stage_kv(kbase, vtbase, ksn, vtn, jt + 1, w, lane);

    // waves whose 16 q rows are entirely above this kv tile skip compute
    // (wave-uniform: only possible on the final tile)
    if (jt * 64 <= qb * 128 + w * 16 + 15) {
      // S^T = K * Q^T : 4 sk-tiles of 16; C-layout: sk = j*16+quad*4+r, q = lr
      f32x4 s_acc[4] = {};
      __builtin_amdgcn_s_setprio(1);
#pragma unroll
      for (int j = 0; j < 4; j++) {
        const bf16* krow = ksc + (j * 16 + lr) * 128;
#pragma unroll
        for (int ks = 0; ks < 4; ks++) {
          bf16x8 kf = *(const bf16x8*)(krow + koff[ks]);
          s_acc[j] = __builtin_amdgcn_mfma_f32_16x16x32_bf16(kf, qf[ks], s_acc[j], 0, 0, 0);
        }
      }
      __builtin_amdgcn_s_setprio(0);

      // causal mask (only the last two tiles can touch the diagonal)
      if (jt >= 2 * qb) {
        int sq = w * 16 + lr;
        int kb0 = jt * 64 - qb * 128;
#pragma unroll
        for (int j = 0; j < 4; j++)
#pragma unroll
          for (int r = 0; r < 4; r++)
            if (kb0 + j * 16 + quad * 4 + r > sq) s_acc[j][r] = -1e30f;
      }

      // online softmax in exp2 domain — per-lane scalars (lane owns q row lr)
      float mx = -1e30f;
#pragma unroll
      for (int j = 0; j < 4; j++)
#pragma unroll
        for (int r = 0; r < 4; r++) mx = fmaxf(mx, s_acc[j][r]);
      mx = fmaxf(mx, __shfl_xor(mx, 16));
      mx = fmaxf(mx, __shfl_xor(mx, 32));

      // defer-max (T13): skip rescale unless the tile max outgrows m_i by >8
      // (P values then bounded by 2^8; f32 accumulation has ample headroom)
      if (!__all(mx <= m_i + 8.f)) {
        float mnew = fmaxf(m_i, mx);
        float alpha = exp2f(m_i - mnew);
        m_i = mnew;
        l_i *= alpha;
#pragma unroll
        for (int n = 0; n < 8; n++)
#pragma unroll
          for (int r = 0; r < 4; r++) o_acc[n][r] *= alpha;
      }

      float p[4][4];
      float sum = 0.f;
#pragma unroll
      for (int j = 0; j < 4; j++)
#pragma unroll
        for (int r = 0; r < 4; r++) {
          p[j][r] = exp2f(s_acc[j][r] - m_i);
          sum += p[j][r];
        }
      sum += __shfl_xor(sum, 16);
      sum += __shfl_xor(sum, 32);
      l_i += sum;

      // pack P into 16x16x16 B-fragments (k = quad*4 + r) — in registers, no LDS
      bf16x4 pf[4];
#pragma unroll
      for (int j = 0; j < 4; j++) {
        pf[j][0] = f2bs(p[j][0]); pf[j][1] = f2bs(p[j][1]);
        pf[j][2] = f2bs(p[j][2]); pf[j][3] = f2bs(p[j][3]);
      }

      // O^T += V^T * P^T  (K=16 per mfma, 4 sk-chunks x 8 d-tiles)
      __builtin_amdgcn_s_setprio(1);
#pragma unroll
      for (int j = 0; j < 4; j++)
#pragma unroll
        for (int n = 0; n < 8; n++) {
          bf16x4 vf = *(const bf16x4*)(vtc + (n * 16 + lr) * 64 + voff[j]);
          o_acc[n] = __builtin_amdgcn_mfma_f32_16x16x16bf16_1k(vf, pf[j], o_acc[n], 0, 0, 0);
        }
      __builtin_amdgcn_s_setprio(0);
    }

    __syncthreads();  // readers done with cur + this wave's DMA into next drained
    bf16* tp;
    tp = ksc; ksc = ksn; ksn = tp;
    tp = vtc; vtc = vtn; vtn = tp;
  }

  // epilogue: O[tok][h*128 + d] = o_acc / l ; d = n*16 + quad*4 + r (4 consecutive)
  {
    float inv_l = 1.f / l_i;
    bf16* obase = O + (size_t)tok * D_MODEL + h * HEAD_DIM + quad * 4;
#pragma unroll
    for (int n = 0; n < 8; n++) {
      bf16x4 ov;
      ov[0] = f2bs(o_acc[n][0] * inv_l); ov[1] = f2bs(o_acc[n][1] * inv_l);
      ov[2] = f2bs(o_acc[n][2] * inv_l); ov[3] = f2bs(o_acc[n][3] * inv_l);
      *(bf16x4*)(obase + n * 16) = ov;
    }
  }
}

// ---------------------------------------------------------------- launcher
extern "C" void kernel_launch(void* const* d_in, const int* in_sizes, int n_in,
                              void* d_out, int out_size, void* d_ws, size_t ws_size,
                              hipStream_t stream) {
  const float* x  = (const float*)d_in[0];
  // d_in[1] = mask: exactly causal (triu k=1) -> hard-coded in flash kernel
  const float* Wq = (const float*)d_in[2];
  const float* Wk = (const float*)d_in[3];
  const float* Wv = (const float*)d_in[4];
  const float* Wo = (const float*)d_in[5];
  float* out = (float*)d_out;

  char* ws = (char*)d_ws;
  const size_t MB = 1024 * 1024;
  bf16* xb   = (bf16*)(ws + 0);         // 32 MB  [4096][4096]
  bf16* WqT  = (bf16*)(ws + 32 * MB);   // 32 MB  (dead after Q gemm; reused as Ob)
  bf16* WkvT = (bf16*)(ws + 64 * MB);   // 16 MB  [2048][4096]: Wk^T rows 0-1023, Wv^T rows 1024-2047
  bf16* WoT  = (bf16*)(ws + 80 * MB);   // 32 MB
  bf16* Qb   = (bf16*)(ws + 112 * MB);  // 32 MB  [4096][4096]
  bf16* KVb  = (bf16*)(ws + 144 * MB);  // 16 MB  [4096][2048]: K cols 0-1023, V cols 1024-2047
  bf16* VTb  = (bf16*)(ws + 160 * MB);  // 8 MB   [B*1024][2048]
  bf16* Ob   = WqT;                     // alias: WqT unused after Q projection

  // 1. cast activations
  cast_f32_to_bf16<<<dim3(NTOK * D_MODEL / 4 / 256), 256, 0, stream>>>(x, xb, NTOK * D_MODEL / 4);
  // 2. transpose-cast weights to [N][K] bf16 (Wk/Wv land adjacent -> fused [2048][4096])
  transpose_cast<<<dim3(D_MODEL / 64, D_MODEL / 64), 256, 0, stream>>>(Wq, WqT, D_MODEL, D_MODEL);
  transpose_cast<<<dim3(1024 / 64, D_MODEL / 64), 256, 0, stream>>>(Wk, WkvT, D_MODEL, 1024);
  transpose_cast<<<dim3(1024 / 64, D_MODEL / 64), 256, 0, stream>>>(Wv, WkvT + (size_t)1024 * 4096, D_MODEL, 1024);
  transpose_cast<<<dim3(D_MODEL / 64, D_MODEL / 64), 256, 0, stream>>>(Wo, WoT, D_MODEL, D_MODEL);
  // 3. projections: Q via 256^2 8-phase; fused K|V via 128^2 (N=2048 -> 512 blocks, 2/CU)
  gemm256<bf16><<<dim3(256), 512, 0, stream>>>(xb, WqT, Qb, NTOK, D_MODEL);
  gemm_bt<bf16><<<dim3(KVSTRIDE / 128, NTOK / 128), 256, 0, stream>>>(xb, WkvT, KVb, NTOK, KVSTRIDE, D_MODEL);
  // 4. RoPE; Q scale = head_dim^-0.5 * log2(e)  (softmax runs in exp2 domain)
  rope_kernel<<<dim3(NTOK * N_HEADS * 64 / 256), 256, 0, stream>>>(Qb, 5, 12, 0.12751741737890f);
  rope_kernel<<<dim3(NTOK * N_KV * 64 / 256), 256, 0, stream>>>(KVb, 3, 11, 1.0f);
  // 5. pre-transpose V (col 1024+ of KVb) per batch: VT[b][c][s]
  transpose_v<<<dim3(1024 / 64, SEQ / 64, BATCH), 256, 0, stream>>>(KVb, VTb);
  // 6. attention (QBLK=128, 8 waves, double-buffered async staging)
  flash_attn<<<dim3(SEQ / 128, N_HEADS, BATCH), 512, 0, stream>>>(Qb, KVb, VTb, Ob);
  // 7. output projection (fp32 out) via 256^2 8-phase
  gemm256<float><<<dim3(256), 512, 0, stream>>>(Ob, WoT, out, NTOK, D_MODEL);
}